// Round 1
// baseline (58.414 us; speedup 1.0000x reference)
//
#include <hip/hip_runtime.h>
#include <hip/hip_bf16.h>

#define ALPHA 0.2f

constexpr int B = 8, N = 2048, F = 64;

typedef __attribute__((ext_vector_type(8))) short bf16x8;
typedef __attribute__((ext_vector_type(16))) float f32x16;

__device__ __forceinline__ float lrelu(float x) { return fmaxf(x, ALPHA * x); }

// ---------------- K1: h = inp@W ; f1 = h@a1 ; f2 = h@a2 ; hT (bf16, transposed per batch)
__global__ __launch_bounds__(256) void k1_project(
    const float* __restrict__ inp, const float* __restrict__ W,
    const float* __restrict__ a,
    __hip_bfloat16* __restrict__ hT, float* __restrict__ f1, float* __restrict__ f2)
{
  __shared__ float Wl[64][64];        // 16KB
  __shared__ float inpl[32][64];      // 8KB
  __shared__ float red[32][8][2];     // 2KB
  __shared__ __hip_bfloat16 hl[32][64]; // 4KB
  __shared__ float al[128];

  const int tid = threadIdx.x;
  const int g0 = blockIdx.x * 32;     // global row in [0, B*N)
  const int b = g0 / N, i0 = g0 % N;

  #pragma unroll
  for (int m = 0; m < 4; ++m) {
    int off = m * 1024 + tid * 4;
    *(float4*)((float*)Wl + off) = *(const float4*)(W + off);
  }
  #pragma unroll
  for (int m = 0; m < 2; ++m) {
    int off = m * 1024 + tid * 4;
    *(float4*)((float*)inpl + off) = *(const float4*)(inp + (size_t)g0 * F + off);
  }
  if (tid < 128) al[tid] = a[tid];
  __syncthreads();

  const int r = tid >> 3, c0 = (tid & 7) * 8;
  float acc[8];
  #pragma unroll
  for (int c = 0; c < 8; ++c) acc[c] = 0.f;
  for (int k = 0; k < 64; ++k) {
    float v = inpl[r][k];
    #pragma unroll
    for (int c = 0; c < 8; ++c) acc[c] += v * Wl[k][c0 + c];
  }
  float p1 = 0.f, p2 = 0.f;
  unsigned short hb[8] __attribute__((aligned(16)));
  #pragma unroll
  for (int c = 0; c < 8; ++c) {
    p1 += acc[c] * al[c0 + c];
    p2 += acc[c] * al[64 + c0 + c];
    __hip_bfloat16 hv = __float2bfloat16(acc[c]);
    hb[c] = *(unsigned short*)&hv;
  }
  red[r][tid & 7][0] = p1;
  red[r][tid & 7][1] = p2;
  *(uint4*)&hl[r][c0] = *(uint4*)hb;
  __syncthreads();

  if (tid < 32) {
    float s1 = 0.f, s2 = 0.f;
    #pragma unroll
    for (int m = 0; m < 8; ++m) { s1 += red[tid][m][0]; s2 += red[tid][m][1]; }
    f1[g0 + tid] = s1;
    f2[g0 + tid] = s2;
  }
  // transposed store: hT[b][c][i0 + r8 .. +8]
  const int c = tid >> 2, r8 = (tid & 3) * 8;
  unsigned short tb[8] __attribute__((aligned(16)));
  #pragma unroll
  for (int m = 0; m < 8; ++m) tb[m] = *(unsigned short*)&hl[r8 + m][c];
  *(uint4*)(hT + ((size_t)b * F + c) * N + i0 + r8) = *(uint4*)tb;
}

// ---------------- K2: per-batch unmasked max of f2 (upper bound for row max)
__global__ __launch_bounds__(256) void k2_f2max(const float* __restrict__ f2,
                                                float* __restrict__ f2max)
{
  __shared__ float s[256];
  const int b = blockIdx.x, tid = threadIdx.x;
  float m = -1e30f;
  for (int j = tid; j < N; j += 256) m = fmaxf(m, f2[b * N + j]);
  s[tid] = m;
  __syncthreads();
  for (int w = 128; w > 0; w >>= 1) {
    if (tid < w) s[tid] = fmaxf(s[tid], s[tid + w]);
    __syncthreads();
  }
  if (tid == 0) f2max[b] = s[0];
}

// ---------------- K3: fused mask + softmax + PV (bf16 MFMA) + elu
__global__ __launch_bounds__(256) void k3_attn(
    const int* __restrict__ adj, const __hip_bfloat16* __restrict__ hT,
    const float* __restrict__ f1, const float* __restrict__ f2,
    const float* __restrict__ f2max, float* __restrict__ out)
{
  constexpr int RT = 32, JT = 128;
  __shared__ __hip_bfloat16 Pl[RT][JT];     // 8KB  (XOR-swizzled)
  __shared__ __hip_bfloat16 hTl[F][JT];     // 16KB (XOR-swizzled)
  __shared__ float rs[RT][8];               // 1KB
  __shared__ float rcp[RT];
  __shared__ float redt[2][32][32];         // 8KB

  const int tid = threadIdx.x;
  const int lane = tid & 63, wid = tid >> 6;
  const int ct = wid >> 1, kh = wid & 1;    // col-tile, k-half
  const int bi = blockIdx.x;
  const int b = bi / (N / RT);
  const int i0 = (bi % (N / RT)) * RT;

  // score-phase mapping: 8 threads per row, 16 j's each
  const int r = tid >> 3, jc = (tid & 7) * 16;
  const float f1r = f1[b * N + i0 + r];
  const float Mr = lrelu(f1r + f2max[b]);   // >= true masked row max (lrelu monotone)

  const int* adjrow = adj + ((size_t)(b * N + i0 + r)) * N + jc;
  const float* f2row = f2 + b * N + jc;
  // hT-stage mapping: 4 threads per feature row, 32 j's each
  const int hc = tid >> 2, js = (tid & 3) * 32;
  const __hip_bfloat16* hrow = hT + ((size_t)b * F + hc) * N + js;

  const int swp = (r & 7) << 3;
  const int swh = (hc & 7) << 3;

  float rowsum = 0.f;
  f32x16 acc;
  #pragma unroll
  for (int q = 0; q < 16; ++q) acc[q] = 0.f;

  for (int t = 0; t < N / JT; ++t) {
    const int j0 = t * JT;
    int4 av[4]; float4 fv[4]; uint4 hv[4];
    #pragma unroll
    for (int m = 0; m < 4; ++m) av[m] = *(const int4*)(adjrow + j0 + m * 4);
    #pragma unroll
    for (int m = 0; m < 4; ++m) fv[m] = *(const float4*)(f2row + j0 + m * 4);
    #pragma unroll
    for (int m = 0; m < 4; ++m) hv[m] = *(const uint4*)(hrow + j0 + m * 8);

    unsigned short pb[16] __attribute__((aligned(16)));
    #pragma unroll
    for (int m = 0; m < 4; ++m) {
      const int* ai = (const int*)&av[m];
      const float* fe = (const float*)&fv[m];
      #pragma unroll
      for (int e = 0; e < 4; ++e) {
        float s = lrelu(f1r + fe[e]);
        float p = (ai[e] > 0) ? __expf(s - Mr) : 0.f;
        __hip_bfloat16 pbf = __float2bfloat16(p);
        rowsum += __bfloat162float(pbf);    // denominator from ROUNDED p -> exact normalization
        pb[m * 4 + e] = *(unsigned short*)&pbf;
      }
    }
    *(uint4*)&Pl[r][jc ^ swp]       = *(uint4*)&pb[0];
    *(uint4*)&Pl[r][(jc + 8) ^ swp] = *(uint4*)&pb[8];
    #pragma unroll
    for (int m = 0; m < 4; ++m)
      *(uint4*)&hTl[hc][(js + m * 8) ^ swh] = hv[m];
    __syncthreads();

    const int arow = lane & 31;
    const int bcol = ct * 32 + (lane & 31);
    const int klo = kh * 64 + ((lane >> 5) * 8);
    #pragma unroll
    for (int s = 0; s < 4; ++s) {
      const int ak = klo + s * 16;
      bf16x8 af = *(const bf16x8*)&Pl[arow][ak ^ ((arow & 7) << 3)];
      bf16x8 bf = *(const bf16x8*)&hTl[bcol][ak ^ ((bcol & 7) << 3)];
      // inline asm avoids builtin operand-type ambiguity (short8 vs __bf16x8)
      asm volatile("v_mfma_f32_32x32x16_bf16 %0, %1, %2, %0"
                   : "+v"(acc) : "v"(af), "v"(bf));
    }
    __syncthreads();
  }

  rs[r][tid & 7] = rowsum;
  if (kh == 1) {
    #pragma unroll
    for (int q = 0; q < 16; ++q)
      redt[ct][(q & 3) + 8 * (q >> 2) + 4 * (lane >> 5)][lane & 31] = acc[q];
  }
  __syncthreads();
  if (tid < 32) {
    float s = 0.f;
    #pragma unroll
    for (int m = 0; m < 8; ++m) s += rs[tid][m];
    rcp[tid] = 1.0f / fmaxf(s, 1e-30f);
  }
  __syncthreads();
  if (kh == 0) {
    #pragma unroll
    for (int q = 0; q < 16; ++q) {
      const int row = (q & 3) + 8 * (q >> 2) + 4 * (lane >> 5);
      float v = (acc[q] + redt[ct][row][lane & 31]) * rcp[row];
      v = v > 0.f ? v : expm1f(v);
      out[((size_t)(b * N + i0 + row)) * F + ct * 32 + (lane & 31)] = v;
    }
  }
}

extern "C" void kernel_launch(void* const* d_in, const int* in_sizes, int n_in,
                              void* d_out, int out_size, void* d_ws, size_t ws_size,
                              hipStream_t stream) {
  const float* inp = (const float*)d_in[0];
  const int*   adj = (const int*)d_in[1];
  const float* W   = (const float*)d_in[2];
  const float* a   = (const float*)d_in[3];
  float* out = (float*)d_out;

  // workspace layout (~2.13 MB): hT bf16 | f1 | f2 | f2max
  char* ws = (char*)d_ws;
  __hip_bfloat16* hT = (__hip_bfloat16*)ws;
  float* f1  = (float*)(ws + (size_t)B * F * N * sizeof(__hip_bfloat16));
  float* f2  = f1 + (size_t)B * N;
  float* f2m = f2 + (size_t)B * N;

  hipLaunchKernelGGL(k1_project, dim3(B * N / 32), dim3(256), 0, stream, inp, W, a, hT, f1, f2);
  hipLaunchKernelGGL(k2_f2max, dim3(B), dim3(256), 0, stream, f2, f2m);
  hipLaunchKernelGGL(k3_attn, dim3(B * N / 32), dim3(256), 0, stream, adj, hT, f1, f2, f2m, out);
}